// Round 1
// baseline (159.470 us; speedup 1.0000x reference)
//
#include <hip/hip_runtime.h>
#include <hip/hip_bf16.h>
#include <math.h>
#include <stdint.h>

// ---------------------------------------------------------------------------
// MultiSimilarityLoss on MI355X.
//   x: [B=4096, D=1024] fp32 (L2-normalized rows), labels: [B] int32
//   out: scalar fp32 = mean over rows of mined multi-similarity loss
// Pipeline (R2):
//   K0: memset gmin=0xFF.., gmax=0      (row-stat atomics init)
//   K1: x fp32 -> bf16 (ws)
//   K2: sim = x_bf16 @ x_bf16^T  -- SYMMETRIC: only 528 upper-tri 128x128
//       blocks; mirror-write transposed tile; per-row min_pos/max_neg
//       computed in epilogue via shfl-reduce + global atomicMin/Max on
//       ordered-uint-encoded floats.
//   K3: per-row mining + loss, SINGLE pass (stats precomputed) -> rowbuf
//   K4: reduce rowbuf -> out[0]
// R1 post-mortem: rowloss was latency/serialization-bound -> per-row store.
// R2 theory: GEMM did 2x the MFMA work (symmetry), rowloss did 2x the sim
//   reads (stats pass). Both halved here.
// ---------------------------------------------------------------------------

#define THRESH    0.5f
#define MARGIN    0.1f
#define SCALE_POS 2.0f
#define SCALE_NEG 40.0f
#define POS_CAP   (1.0f - 1e-5f)

typedef __bf16 bf16x8 __attribute__((ext_vector_type(8)));
typedef float  f32x4  __attribute__((ext_vector_type(4)));

// ---- fp32 -> bf16 (RNE) ----------------------------------------------------
__device__ __forceinline__ uint16_t f2bf(float f) {
  union { float f; uint32_t u; } v; v.f = f;
  uint32_t u = v.u;
  u += 0x7FFFu + ((u >> 16) & 1u);
  return (uint16_t)(u >> 16);
}

// ---- order-preserving float<->uint encode (for atomicMin/Max on floats) ----
__device__ __forceinline__ uint32_t fenc(float f) {
  union { float f; uint32_t u; } v; v.f = f;
  return (v.u & 0x80000000u) ? ~v.u : (v.u ^ 0x80000000u);
}
__device__ __forceinline__ float fdec(uint32_t k) {
  union { float f; uint32_t u; } v;
  v.u = (k & 0x80000000u) ? (k ^ 0x80000000u) : ~k;
  return v.f;
}

__global__ __launch_bounds__(256) void cvt_bf16_kernel(
    const float* __restrict__ x, uint16_t* __restrict__ y, int n) {
  int i = (blockIdx.x * 256 + threadIdx.x) * 4;
  if (i + 3 < n) {
    float4 v = *(const float4*)(x + i);
    ushort4 o;
    o.x = f2bf(v.x); o.y = f2bf(v.y); o.z = f2bf(v.z); o.w = f2bf(v.w);
    *(ushort4*)(y + i) = o;
  }
}

// ---- async global->LDS staging (16B / lane) --------------------------------
#if defined(__has_builtin)
#if __has_builtin(__builtin_amdgcn_global_load_lds)
#define HAVE_GLL 1
#endif
#endif

__device__ __forceinline__ void stage16(const uint16_t* g, uint16_t* lds_wave_base, int lane) {
#ifdef HAVE_GLL
  __builtin_amdgcn_global_load_lds(
      (const __attribute__((address_space(1))) void*)g,
      (__attribute__((address_space(3))) void*)lds_wave_base, 16, 0, 0);
#else
  *(uint4*)(lds_wave_base + lane * 8) = *(const uint4*)g;
#endif
}

// ---- sim = X @ X^T, upper-triangle 128x128 tiles + mirror + row stats ------
__global__ __launch_bounds__(256) void simgemm_kernel(
    const uint16_t* __restrict__ X, const int* __restrict__ labels,
    float* __restrict__ C, uint32_t* __restrict__ gmin, uint32_t* __restrict__ gmax,
    int B, int D) {
  __shared__ __align__(16) uint16_t sA[128 * 32];
  __shared__ __align__(16) uint16_t sB[128 * 32];
  __shared__ int slabR[128];
  __shared__ int slabC[128];

  // triangular decode: blockIdx.x -> (bi, bj), bi <= bj
  int t = blockIdx.x;
  const int nblk = B >> 7;
  int bi = 0;
  while (t >= nblk - bi) { t -= nblk - bi; ++bi; }
  const int bj = bi + t;
  const int bm = bi * 128;
  const int bn = bj * 128;

  const int tid  = threadIdx.x;
  const int wave = tid >> 6;
  const int lane = tid & 63;
  const int waveM = wave >> 1, waveN = wave & 1;

  if (tid < 128) slabR[tid] = labels[bm + tid];
  else           slabC[tid - 128] = labels[bn + tid - 128];

  const uint16_t* gA = X + (size_t)bm * D;
  const uint16_t* gB = X + (size_t)bn * D;

  uint16_t* lA0 = sA + wave * 512;
  uint16_t* lA1 = sA + 2048 + wave * 512;
  uint16_t* lB0 = sB + wave * 512;
  uint16_t* lB1 = sB + 2048 + wave * 512;

  const int r0 = tid >> 2,           c0 = (tid & 3) * 8;
  const int r1 = (tid + 256) >> 2,   c1 = (tid & 3) * 8;

  const int fr = lane & 15;
  const int fq = lane >> 4;
  const int aoff = (waveM * 64 + fr) * 32 + fq * 8;
  const int boff = (waveN * 64 + fr) * 32 + fq * 8;

  f32x4 acc[4][4] = {};

  for (int k0 = 0; k0 < D; k0 += 32) {
    stage16(gA + (size_t)r0 * D + k0 + c0, lA0, lane);
    stage16(gA + (size_t)r1 * D + k0 + c1, lA1, lane);
    stage16(gB + (size_t)r0 * D + k0 + c0, lB0, lane);
    stage16(gB + (size_t)r1 * D + k0 + c1, lB1, lane);
    __syncthreads();

    bf16x8 af[4], bfv[4];
#pragma unroll
    for (int tt = 0; tt < 4; ++tt) af[tt]  = *(const bf16x8*)(sA + aoff + tt * 512);
#pragma unroll
    for (int tt = 0; tt < 4; ++tt) bfv[tt] = *(const bf16x8*)(sB + boff + tt * 512);

#pragma unroll
    for (int mt = 0; mt < 4; ++mt)
#pragma unroll
      for (int nt = 0; nt < 4; ++nt)
        acc[mt][nt] = __builtin_amdgcn_mfma_f32_16x16x32_bf16(
            af[mt], bfv[nt], acc[mt][nt], 0, 0, 0);
    __syncthreads();
  }

  // ---- direct write C[bm..][bn..] -----------------------------------------
#pragma unroll
  for (int mt = 0; mt < 4; ++mt) {
#pragma unroll
    for (int nt = 0; nt < 4; ++nt) {
      const int col = bn + waveN * 64 + nt * 16 + fr;
#pragma unroll
      for (int r = 0; r < 4; ++r) {
        const int row = bm + waveM * 64 + mt * 16 + fq * 4 + r;
        C[(size_t)row * B + col] = acc[mt][nt][r];
      }
    }
  }

  // ---- mirror write C[bn..][bm..] = tile^T (contiguous float4 per lane) ---
  if (bi != bj) {
#pragma unroll
    for (int mt = 0; mt < 4; ++mt) {
#pragma unroll
      for (int nt = 0; nt < 4; ++nt) {
        const int col  = bn + waveN * 64 + nt * 16 + fr;
        const int rowb = bm + waveM * 64 + mt * 16 + fq * 4;
        *(f32x4*)(C + (size_t)col * B + rowb) = acc[mt][nt];
      }
    }
  }

  // ---- per-row stats: min positive (valid), max negative ------------------
  const float INF = __builtin_inff();

  int lr[4][4];
#pragma unroll
  for (int mt = 0; mt < 4; ++mt)
#pragma unroll
    for (int r = 0; r < 4; ++r)
      lr[mt][r] = slabR[waveM * 64 + mt * 16 + fq * 4 + r];
  int lc[4];
#pragma unroll
  for (int nt = 0; nt < 4; ++nt) lc[nt] = slabC[waveN * 64 + nt * 16 + fr];

  // row-side: rows of this tile (bm-range) over cols (bn-range)
  {
    float rmin[4][4], rmax[4][4];
#pragma unroll
    for (int mt = 0; mt < 4; ++mt)
#pragma unroll
      for (int r = 0; r < 4; ++r) { rmin[mt][r] = INF; rmax[mt][r] = -INF; }

#pragma unroll
    for (int mt = 0; mt < 4; ++mt) {
#pragma unroll
      for (int nt = 0; nt < 4; ++nt) {
        const int gcol = bn + waveN * 64 + nt * 16 + fr;
#pragma unroll
        for (int r = 0; r < 4; ++r) {
          const int grow = bm + waveM * 64 + mt * 16 + fq * 4 + r;
          const float s = acc[mt][nt][r];
          if (lr[mt][r] == lc[nt]) {
            if (grow != gcol && s < POS_CAP) rmin[mt][r] = fminf(rmin[mt][r], s);
          } else {
            rmax[mt][r] = fmaxf(rmax[mt][r], s);
          }
        }
      }
    }
    // reduce across fr (lane bits 0..3); lanes with same fq hold same rows
#pragma unroll
    for (int mt = 0; mt < 4; ++mt)
#pragma unroll
      for (int r = 0; r < 4; ++r) {
#pragma unroll
        for (int m = 1; m < 16; m <<= 1) {
          rmin[mt][r] = fminf(rmin[mt][r], __shfl_xor(rmin[mt][r], m, 64));
          rmax[mt][r] = fmaxf(rmax[mt][r], __shfl_xor(rmax[mt][r], m, 64));
        }
      }
    if (fr == 0) {
#pragma unroll
      for (int mt = 0; mt < 4; ++mt)
#pragma unroll
        for (int r = 0; r < 4; ++r) {
          const int grow = bm + waveM * 64 + mt * 16 + fq * 4 + r;
          if (rmin[mt][r] < INF)  atomicMin(&gmin[grow], fenc(rmin[mt][r]));
          if (rmax[mt][r] > -INF) atomicMax(&gmax[grow], fenc(rmax[mt][r]));
        }
    }
  }

  // col-side: rows of the MIRRORED tile (bn-range) over cols (bm-range)
  if (bi != bj) {
    float cmin[4], cmax[4];
#pragma unroll
    for (int nt = 0; nt < 4; ++nt) { cmin[nt] = INF; cmax[nt] = -INF; }

#pragma unroll
    for (int nt = 0; nt < 4; ++nt) {
      const int gcol = bn + waveN * 64 + nt * 16 + fr;
#pragma unroll
      for (int mt = 0; mt < 4; ++mt) {
#pragma unroll
        for (int r = 0; r < 4; ++r) {
          const int grow = bm + waveM * 64 + mt * 16 + fq * 4 + r;
          const float s = acc[mt][nt][r];
          if (lc[nt] == lr[mt][r]) {
            if (grow != gcol && s < POS_CAP) cmin[nt] = fminf(cmin[nt], s);
          } else {
            cmax[nt] = fmaxf(cmax[nt], s);
          }
        }
      }
    }
    // reduce across fq (lane bits 4..5); lanes with same fr hold same cols
#pragma unroll
    for (int nt = 0; nt < 4; ++nt) {
#pragma unroll
      for (int m = 16; m < 64; m <<= 1) {
        cmin[nt] = fminf(cmin[nt], __shfl_xor(cmin[nt], m, 64));
        cmax[nt] = fmaxf(cmax[nt], __shfl_xor(cmax[nt], m, 64));
      }
    }
    if (fq == 0) {
#pragma unroll
      for (int nt = 0; nt < 4; ++nt) {
        const int gcol = bn + waveN * 64 + nt * 16 + fr;
        if (cmin[nt] < INF)  atomicMin(&gmin[gcol], fenc(cmin[nt]));
        if (cmax[nt] > -INF) atomicMax(&gmax[gcol], fenc(cmax[nt]));
      }
    }
  }
}

// ---- per-row mining + loss, single pass (stats precomputed) ----------------
// 4 rows per block; labels staged once per block.
__global__ __launch_bounds__(256) void rowloss_kernel(
    const float* __restrict__ sim, const int* __restrict__ labels,
    const uint32_t* __restrict__ gmin, const uint32_t* __restrict__ gmax,
    float* __restrict__ rowbuf, int B) {
  __shared__ int   slab[4096];
  __shared__ float red[8];

  const int tid  = threadIdx.x;
  const int wave = tid >> 6;
  const int lane = tid & 63;
  const float INF = __builtin_inff();

  for (int tq = tid; tq < (B >> 2); tq += 256)
    ((int4*)slab)[tq] = ((const int4*)labels)[tq];
  __syncthreads();

  const int iters = B >> 10;  // float4 per thread per row
  for (int rr = 0; rr < 4; ++rr) {
    const int i = blockIdx.x * 4 + rr;
    const float* row = sim + (size_t)i * B;
    const int li = slab[i];

    const uint32_t kmin = gmin[i], kmax = gmax[i];
    const bool haspos = (kmin != 0xFFFFFFFFu);
    const bool hasneg = (kmax != 0u);
    const float minpos = haspos ? fdec(kmin) : INF;
    const float maxneg = hasneg ? fdec(kmax) : -INF;

    float psum = 0.f, nsum = 0.f;
    for (int it = 0; it < iters; ++it) {
      const int j = it * 1024 + tid * 4;
      float4 v = *(const float4*)(row + j);
      float s4[4] = {v.x, v.y, v.z, v.w};
#pragma unroll
      for (int q = 0; q < 4; ++q) {
        const int jj = j + q;
        const float s = s4[q];
        if (slab[jj] == li) {
          if (jj != i && s < POS_CAP && (s - MARGIN < maxneg))
            psum += __expf(-SCALE_POS * (s - THRESH));
        } else {
          if (s + MARGIN > minpos)
            nsum += __expf(SCALE_NEG * (s - THRESH));
        }
      }
    }

#pragma unroll
    for (int m = 32; m > 0; m >>= 1) {
      psum += __shfl_xor(psum, m, 64);
      nsum += __shfl_xor(nsum, m, 64);
    }
    if (lane == 0) { red[wave] = psum; red[4 + wave] = nsum; }
    __syncthreads();

    if (tid == 0) {
      psum = red[0] + red[1] + red[2] + red[3];
      nsum = red[4] + red[5] + red[6] + red[7];
      const bool has_row = haspos && hasneg && (psum > 0.f) && (nsum > 0.f);
      rowbuf[i] = has_row
          ? (log1pf(psum) * (1.0f / SCALE_POS) + log1pf(nsum) * (1.0f / SCALE_NEG))
          : 0.f;
    }
    __syncthreads();  // red[] reused next row
  }
}

// ---- final reduction: 4096 floats -> out[0] --------------------------------
__global__ __launch_bounds__(256) void finalreduce_kernel(
    const float* __restrict__ rowbuf, float* __restrict__ out, int B) {
  __shared__ float red[4];
  const int tid  = threadIdx.x;
  const int wave = tid >> 6;
  const int lane = tid & 63;

  float s = 0.f;
  for (int j = tid * 4; j < B; j += 1024) {
    float4 v = *(const float4*)(rowbuf + j);
    s += v.x + v.y + v.z + v.w;
  }
#pragma unroll
  for (int m = 32; m > 0; m >>= 1) s += __shfl_xor(s, m, 64);
  if (lane == 0) red[wave] = s;
  __syncthreads();
  if (tid == 0)
    out[0] = (red[0] + red[1] + red[2] + red[3]) * (1.0f / (float)B);
}

// ---------------------------------------------------------------------------
extern "C" void kernel_launch(void* const* d_in, const int* in_sizes, int n_in,
                              void* d_out, int out_size, void* d_ws, size_t ws_size,
                              hipStream_t stream) {
  const float* x      = (const float*)d_in[0];
  const int*   labels = (const int*)d_in[1];
  float*       out    = (float*)d_out;

  const int B = in_sizes[1];           // 4096
  const int D = in_sizes[0] / B;       // 1024

  uint16_t* xbf = (uint16_t*)d_ws;
  size_t xbytes = (((size_t)B * D * 2) + 255) & ~(size_t)255;
  float* sim = (float*)((char*)d_ws + xbytes);
  size_t simbytes = (size_t)B * B * 4;
  float* rowbuf = (float*)((char*)d_ws + xbytes + simbytes);
  uint32_t* gmin = (uint32_t*)((char*)d_ws + xbytes + simbytes + (size_t)B * 4);
  uint32_t* gmax = (uint32_t*)((char*)d_ws + xbytes + simbytes + (size_t)B * 8);

  // stat init: gmin = +inf sentinel (all ones), gmax = -inf sentinel (zero)
  hipMemsetAsync(gmin, 0xFF, (size_t)B * 4, stream);
  hipMemsetAsync(gmax, 0x00, (size_t)B * 4, stream);

  const int n = B * D;
  cvt_bf16_kernel<<<n / 1024, 256, 0, stream>>>(x, xbf, n);

  const int nblk = B / 128;
  const int nb   = nblk * (nblk + 1) / 2;   // 528 upper-triangle tiles
  simgemm_kernel<<<nb, 256, 0, stream>>>(xbf, labels, sim, gmin, gmax, B, D);

  rowloss_kernel<<<B / 4, 256, 0, stream>>>(sim, labels, gmin, gmax, rowbuf, B);
  finalreduce_kernel<<<1, 256, 0, stream>>>(rowbuf, out, B);
}

// Round 2
// 148.133 us; speedup vs baseline: 1.0765x; 1.0765x over previous
//
#include <hip/hip_runtime.h>
#include <hip/hip_bf16.h>
#include <math.h>
#include <stdint.h>

// ---------------------------------------------------------------------------
// MultiSimilarityLoss on MI355X.
//   x: [B=4096, D=1024] fp32 (L2-normalized rows), labels: [B] int32
//   out: scalar fp32 = mean over rows of mined multi-similarity loss
// Pipeline (R3):
//   K0: memset gmin=0xFF.., gmax=0
//   K1: x fp32 -> bf16
//   K2: sim = x @ x^T, 528 upper-tri 128x128 blocks, BK=64, double-buffered
//       LDS with 2-phase prefetch (issue next tile's global_load_lds BEFORE
//       compute, one barrier per tile). T2 XOR-swizzle (both-sides: linear
//       gll dest + inverse-swizzled global src + swizzled ds_read).
//       Mirror-write transposed tile; fused per-row min_pos/max_neg stats
//       via shfl-reduce + ordered-uint atomicMin/Max.
//   K3: per-row mining + loss, single pass -> rowbuf
//   K4: reduce rowbuf -> out[0]
// R2 post-mortem: simgemm 80us, MfmaUtil 8.4%, HBM 17% -> latency-bound:
//   BK=32 loop drained vmcnt(0) every iter with ~2 blocks/CU. R3 overlaps
//   load latency with compute (T3 minimum 2-phase) and halves barrier count.
// ---------------------------------------------------------------------------

#define THRESH    0.5f
#define MARGIN    0.1f
#define SCALE_POS 2.0f
#define SCALE_NEG 40.0f
#define POS_CAP   (1.0f - 1e-5f)

typedef __bf16 bf16x8 __attribute__((ext_vector_type(8)));
typedef float  f32x4  __attribute__((ext_vector_type(4)));

// ---- fp32 -> bf16 (RNE) ----------------------------------------------------
__device__ __forceinline__ uint16_t f2bf(float f) {
  union { float f; uint32_t u; } v; v.f = f;
  uint32_t u = v.u;
  u += 0x7FFFu + ((u >> 16) & 1u);
  return (uint16_t)(u >> 16);
}

// ---- order-preserving float<->uint encode (for atomicMin/Max on floats) ----
__device__ __forceinline__ uint32_t fenc(float f) {
  union { float f; uint32_t u; } v; v.f = f;
  return (v.u & 0x80000000u) ? ~v.u : (v.u ^ 0x80000000u);
}
__device__ __forceinline__ float fdec(uint32_t k) {
  union { float f; uint32_t u; } v;
  v.u = (k & 0x80000000u) ? (k ^ 0x80000000u) : ~k;
  return v.f;
}

__global__ __launch_bounds__(256) void cvt_bf16_kernel(
    const float* __restrict__ x, uint16_t* __restrict__ y, int n) {
  int i = (blockIdx.x * 256 + threadIdx.x) * 4;
  if (i + 3 < n) {
    float4 v = *(const float4*)(x + i);
    ushort4 o;
    o.x = f2bf(v.x); o.y = f2bf(v.y); o.z = f2bf(v.z); o.w = f2bf(v.w);
    *(ushort4*)(y + i) = o;
  }
}

// ---- async global->LDS staging (16B / lane) --------------------------------
#if defined(__has_builtin)
#if __has_builtin(__builtin_amdgcn_global_load_lds)
#define HAVE_GLL 1
#endif
#endif

__device__ __forceinline__ void stage16(const uint16_t* g, uint16_t* lds_wave_base, int lane) {
#ifdef HAVE_GLL
  __builtin_amdgcn_global_load_lds(
      (const __attribute__((address_space(1))) void*)g,
      (__attribute__((address_space(3))) void*)lds_wave_base, 16, 0, 0);
#else
  *(uint4*)(lds_wave_base + lane * 8) = *(const uint4*)g;
#endif
}

// ---- sim = X @ X^T, upper-tri 128x128 tiles, BK=64, 2-phase dbuf -----------
__global__ __launch_bounds__(256) void simgemm_kernel(
    const uint16_t* __restrict__ X, const int* __restrict__ labels,
    float* __restrict__ C, uint32_t* __restrict__ gmin, uint32_t* __restrict__ gmax,
    int B, int D) {
  // [buf][A=0/B=1][128 rows][64 cols] bf16, 64 KiB total
  __shared__ __align__(16) uint16_t sT[2][2][128 * 64];
  __shared__ int slabR[128];
  __shared__ int slabC[128];

  const int nblk = B >> 7;
  const int nb   = nblk * (nblk + 1) / 2;

  // XCD-aware bijective swizzle (nb % 8 == 0 for B=4096): consecutive tri
  // indices share the A row-panel -> keep them on one XCD's L2.
  int t = blockIdx.x;
  if ((nb & 7) == 0) {
    const int cpx = nb >> 3;
    t = (t % 8) * cpx + t / 8;
  }
  // triangular decode: t -> (bi, bj), bi <= bj
  int bi = 0;
  while (t >= nblk - bi) { t -= nblk - bi; ++bi; }
  const int bj = bi + t;
  const int bm = bi * 128;
  const int bn = bj * 128;

  const int tid  = threadIdx.x;
  const int wave = tid >> 6;
  const int lane = tid & 63;
  const int waveM = wave >> 1, waveN = wave & 1;

  if (tid < 128) slabR[tid] = labels[bm + tid];
  else           slabC[tid - 128] = labels[bn + tid - 128];

  const uint16_t* gA = X + (size_t)bm * D;
  const uint16_t* gB = X + (size_t)bn * D;

  // staging map: LDS linear 16B-chunk idx = s*256 + tid (s = call-site 0..3)
  //   row = idx>>3 (128B rows), within-row byte = (idx&7)<<4,
  //   inverse-swizzled global column byte = ((idx&7)<<4) ^ ((row&7)<<4)
  int srcOff[4];
#pragma unroll
  for (int s = 0; s < 4; ++s) {
    const int idx = s * 256 + tid;
    const int row = idx >> 3;
    const int cb  = ((idx & 7) << 4) ^ ((row & 7) << 4);  // byte in row
    srcOff[s] = row * D + (cb >> 1);                      // elem offset
  }

  const int fr = lane & 15;
  const int fq = lane >> 4;
  const int sw = (fr & 7) << 4;   // read-side swizzle (row&7 == fr&7)

  f32x4 acc[4][4] = {};

  const int NT = D >> 6;          // 64-wide K tiles

  // prologue: stage tile 0 into buf 0
#pragma unroll
  for (int s = 0; s < 4; ++s) {
    uint16_t* dA = &sT[0][0][0] + (s * 256 + wave * 64) * 8;
    uint16_t* dB = &sT[0][1][0] + (s * 256 + wave * 64) * 8;
    stage16(gA + srcOff[s], dA, lane);
    stage16(gB + srcOff[s], dB, lane);
  }
  __syncthreads();

  int cur = 0;
  for (int kt = 0; kt < NT; ++kt) {
    // prefetch tile kt+1 into the other buffer (issued, NOT waited)
    if (kt + 1 < NT) {
      const int k0 = (kt + 1) << 6;
#pragma unroll
      for (int s = 0; s < 4; ++s) {
        uint16_t* dA = &sT[cur ^ 1][0][0] + (s * 256 + wave * 64) * 8;
        uint16_t* dB = &sT[cur ^ 1][1][0] + (s * 256 + wave * 64) * 8;
        stage16(gA + srcOff[s] + k0, dA, lane);
        stage16(gB + srcOff[s] + k0, dB, lane);
      }
    }

    // compute on current buffer: 2 x K=32 rounds, 16 MFMA each
    const char* tA = (const char*)&sT[cur][0][0];
    const char* tB = (const char*)&sT[cur][1][0];
#pragma unroll
    for (int kk = 0; kk < 2; ++kk) {
      const int cbyte = (kk * 64 + fq * 16) ^ sw;
      bf16x8 af[4], bfv[4];
#pragma unroll
      for (int mt = 0; mt < 4; ++mt) {
        const int rowa = waveM * 64 + mt * 16 + fr;
        af[mt] = *(const bf16x8*)(tA + rowa * 128 + cbyte);
      }
#pragma unroll
      for (int nt = 0; nt < 4; ++nt) {
        const int rowb = waveN * 64 + nt * 16 + fr;
        bfv[nt] = *(const bf16x8*)(tB + rowb * 128 + cbyte);
      }
#pragma unroll
      for (int mt = 0; mt < 4; ++mt)
#pragma unroll
        for (int nt = 0; nt < 4; ++nt)
          acc[mt][nt] = __builtin_amdgcn_mfma_f32_16x16x32_bf16(
              af[mt], bfv[nt], acc[mt][nt], 0, 0, 0);
    }

    __syncthreads();   // drains vmcnt (prefetch landed) + lgkm; swap buffers
    cur ^= 1;
  }

  // ---- direct write C[bm..][bn..] -----------------------------------------
#pragma unroll
  for (int mt = 0; mt < 4; ++mt) {
#pragma unroll
    for (int nt = 0; nt < 4; ++nt) {
      const int col = bn + waveN * 64 + nt * 16 + fr;
#pragma unroll
      for (int r = 0; r < 4; ++r) {
        const int row = bm + waveM * 64 + mt * 16 + fq * 4 + r;
        C[(size_t)row * B + col] = acc[mt][nt][r];
      }
    }
  }

  // ---- mirror write C[bn..][bm..] = tile^T (contiguous float4 per lane) ---
  if (bi != bj) {
#pragma unroll
    for (int mt = 0; mt < 4; ++mt) {
#pragma unroll
      for (int nt = 0; nt < 4; ++nt) {
        const int col  = bn + waveN * 64 + nt * 16 + fr;
        const int rowb = bm + waveM * 64 + mt * 16 + fq * 4;
        *(f32x4*)(C + (size_t)col * B + rowb) = acc[mt][nt];
      }
    }
  }

  // ---- per-row stats: min positive (valid), max negative ------------------
  const float INF = __builtin_inff();

  int lr[4][4];
#pragma unroll
  for (int mt = 0; mt < 4; ++mt)
#pragma unroll
    for (int r = 0; r < 4; ++r)
      lr[mt][r] = slabR[waveM * 64 + mt * 16 + fq * 4 + r];
  int lc[4];
#pragma unroll
  for (int nt = 0; nt < 4; ++nt) lc[nt] = slabC[waveN * 64 + nt * 16 + fr];

  // row-side: rows of this tile (bm-range) over cols (bn-range)
  {
    float rmin[4][4], rmax[4][4];
#pragma unroll
    for (int mt = 0; mt < 4; ++mt)
#pragma unroll
      for (int r = 0; r < 4; ++r) { rmin[mt][r] = INF; rmax[mt][r] = -INF; }

#pragma unroll
    for (int mt = 0; mt < 4; ++mt) {
#pragma unroll
      for (int nt = 0; nt < 4; ++nt) {
        const int gcol = bn + waveN * 64 + nt * 16 + fr;
#pragma unroll
        for (int r = 0; r < 4; ++r) {
          const int grow = bm + waveM * 64 + mt * 16 + fq * 4 + r;
          const float s = acc[mt][nt][r];
          if (lr[mt][r] == lc[nt]) {
            if (grow != gcol && s < POS_CAP) rmin[mt][r] = fminf(rmin[mt][r], s);
          } else {
            rmax[mt][r] = fmaxf(rmax[mt][r], s);
          }
        }
      }
    }
    // reduce across fr (lane bits 0..3); lanes with same fq hold same rows
#pragma unroll
    for (int mt = 0; mt < 4; ++mt)
#pragma unroll
      for (int r = 0; r < 4; ++r) {
#pragma unroll
        for (int m = 1; m < 16; m <<= 1) {
          rmin[mt][r] = fminf(rmin[mt][r], __shfl_xor(rmin[mt][r], m, 64));
          rmax[mt][r] = fmaxf(rmax[mt][r], __shfl_xor(rmax[mt][r], m, 64));
        }
      }
    if (fr == 0) {
#pragma unroll
      for (int mt = 0; mt < 4; ++mt)
#pragma unroll
        for (int r = 0; r < 4; ++r) {
          const int grow = bm + waveM * 64 + mt * 16 + fq * 4 + r;
          if (rmin[mt][r] < INF)  atomicMin(&gmin[grow], fenc(rmin[mt][r]));
          if (rmax[mt][r] > -INF) atomicMax(&gmax[grow], fenc(rmax[mt][r]));
        }
    }
  }

  // col-side: rows of the MIRRORED tile (bn-range) over cols (bm-range)
  if (bi != bj) {
    float cmin[4], cmax[4];
#pragma unroll
    for (int nt = 0; nt < 4; ++nt) { cmin[nt] = INF; cmax[nt] = -INF; }

#pragma unroll
    for (int nt = 0; nt < 4; ++nt) {
      const int gcol = bn + waveN * 64 + nt * 16 + fr;
#pragma unroll
      for (int mt = 0; mt < 4; ++mt) {
#pragma unroll
        for (int r = 0; r < 4; ++r) {
          const int grow = bm + waveM * 64 + mt * 16 + fq * 4 + r;
          const float s = acc[mt][nt][r];
          if (lc[nt] == lr[mt][r]) {
            if (grow != gcol && s < POS_CAP) cmin[nt] = fminf(cmin[nt], s);
          } else {
            cmax[nt] = fmaxf(cmax[nt], s);
          }
        }
      }
    }
    // reduce across fq (lane bits 4..5); lanes with same fr hold same cols
#pragma unroll
    for (int nt = 0; nt < 4; ++nt) {
#pragma unroll
      for (int m = 16; m < 64; m <<= 1) {
        cmin[nt] = fminf(cmin[nt], __shfl_xor(cmin[nt], m, 64));
        cmax[nt] = fmaxf(cmax[nt], __shfl_xor(cmax[nt], m, 64));
      }
    }
    if (fq == 0) {
#pragma unroll
      for (int nt = 0; nt < 4; ++nt) {
        const int gcol = bn + waveN * 64 + nt * 16 + fr;
        if (cmin[nt] < INF)  atomicMin(&gmin[gcol], fenc(cmin[nt]));
        if (cmax[nt] > -INF) atomicMax(&gmax[gcol], fenc(cmax[nt]));
      }
    }
  }
}

// ---- per-row mining + loss, single pass (stats precomputed) ----------------
__global__ __launch_bounds__(256) void rowloss_kernel(
    const float* __restrict__ sim, const int* __restrict__ labels,
    const uint32_t* __restrict__ gmin, const uint32_t* __restrict__ gmax,
    float* __restrict__ rowbuf, int B) {
  __shared__ int   slab[4096];
  __shared__ float red[8];

  const int tid  = threadIdx.x;
  const int wave = tid >> 6;
  const int lane = tid & 63;
  const float INF = __builtin_inff();

  for (int tq = tid; tq < (B >> 2); tq += 256)
    ((int4*)slab)[tq] = ((const int4*)labels)[tq];
  __syncthreads();

  const int iters = B >> 10;  // float4 per thread per row
  for (int rr = 0; rr < 4; ++rr) {
    const int i = blockIdx.x * 4 + rr;
    const float* row = sim + (size_t)i * B;
    const int li = slab[i];

    const uint32_t kmin = gmin[i], kmax = gmax[i];
    const bool haspos = (kmin != 0xFFFFFFFFu);
    const bool hasneg = (kmax != 0u);
    const float minpos = haspos ? fdec(kmin) : INF;
    const float maxneg = hasneg ? fdec(kmax) : -INF;

    float psum = 0.f, nsum = 0.f;
    for (int it = 0; it < iters; ++it) {
      const int j = it * 1024 + tid * 4;
      float4 v = *(const float4*)(row + j);
      float s4[4] = {v.x, v.y, v.z, v.w};
#pragma unroll
      for (int q = 0; q < 4; ++q) {
        const int jj = j + q;
        const float s = s4[q];
        if (slab[jj] == li) {
          if (jj != i && s < POS_CAP && (s - MARGIN < maxneg))
            psum += __expf(-SCALE_POS * (s - THRESH));
        } else {
          if (s + MARGIN > minpos)
            nsum += __expf(SCALE_NEG * (s - THRESH));
        }
      }
    }

#pragma unroll
    for (int m = 32; m > 0; m >>= 1) {
      psum += __shfl_xor(psum, m, 64);
      nsum += __shfl_xor(nsum, m, 64);
    }
    if (lane == 0) { red[wave] = psum; red[4 + wave] = nsum; }
    __syncthreads();

    if (tid == 0) {
      psum = red[0] + red[1] + red[2] + red[3];
      nsum = red[4] + red[5] + red[6] + red[7];
      const bool has_row = haspos && hasneg && (psum > 0.f) && (nsum > 0.f);
      rowbuf[i] = has_row
          ? (log1pf(psum) * (1.0f / SCALE_POS) + log1pf(nsum) * (1.0f / SCALE_NEG))
          : 0.f;
    }
    __syncthreads();  // red[] reused next row
  }
}

// ---- final reduction: 4096 floats -> out[0] --------------------------------
__global__ __launch_bounds__(256) void finalreduce_kernel(
    const float* __restrict__ rowbuf, float* __restrict__ out, int B) {
  __shared__ float red[4];
  const int tid  = threadIdx.x;
  const int wave = tid >> 6;
  const int lane = tid & 63;

  float s = 0.f;
  for (int j = tid * 4; j < B; j += 1024) {
    float4 v = *(const float4*)(rowbuf + j);
    s += v.x + v.y + v.z + v.w;
  }
#pragma unroll
  for (int m = 32; m > 0; m >>= 1) s += __shfl_xor(s, m, 64);
  if (lane == 0) red[wave] = s;
  __syncthreads();
  if (tid == 0)
    out[0] = (red[0] + red[1] + red[2] + red[3]) * (1.0f / (float)B);
}

// ---------------------------------------------------------------------------
extern "C" void kernel_launch(void* const* d_in, const int* in_sizes, int n_in,
                              void* d_out, int out_size, void* d_ws, size_t ws_size,
                              hipStream_t stream) {
  const float* x      = (const float*)d_in[0];
  const int*   labels = (const int*)d_in[1];
  float*       out    = (float*)d_out;

  const int B = in_sizes[1];           // 4096
  const int D = in_sizes[0] / B;       // 1024

  uint16_t* xbf = (uint16_t*)d_ws;
  size_t xbytes = (((size_t)B * D * 2) + 255) & ~(size_t)255;
  float* sim = (float*)((char*)d_ws + xbytes);
  size_t simbytes = (size_t)B * B * 4;
  float* rowbuf = (float*)((char*)d_ws + xbytes + simbytes);
  uint32_t* gmin = (uint32_t*)((char*)d_ws + xbytes + simbytes + (size_t)B * 4);
  uint32_t* gmax = (uint32_t*)((char*)d_ws + xbytes + simbytes + (size_t)B * 8);

  hipMemsetAsync(gmin, 0xFF, (size_t)B * 4, stream);
  hipMemsetAsync(gmax, 0x00, (size_t)B * 4, stream);

  const int n = B * D;
  cvt_bf16_kernel<<<n / 1024, 256, 0, stream>>>(x, xbf, n);

  const int nblk = B / 128;
  const int nb   = nblk * (nblk + 1) / 2;   // 528 upper-triangle tiles
  simgemm_kernel<<<nb, 256, 0, stream>>>(xbf, labels, sim, gmin, gmax, B, D);

  rowloss_kernel<<<B / 4, 256, 0, stream>>>(sim, labels, gmin, gmax, rowbuf, B);
  finalreduce_kernel<<<1, 256, 0, stream>>>(rowbuf, out, B);
}